// Round 1
// baseline (714.423 us; speedup 1.0000x reference)
//
#include <hip/hip_runtime.h>
#include <math.h>

#define NN 20000
#define RR 32
#define HH 64
#define CC 8
#define EE 640000

// ---------------------------------------------------------------- layer 1
// h[n][k] = root1[n][k] + bias1[k]
__global__ __launch_bounds__(256) void k_init_h(const float* __restrict__ root1,
                                                const float* __restrict__ bias1,
                                                float* __restrict__ h) {
    int i = blockIdx.x * 256 + threadIdx.x;  // 0 .. NN*HH
    if (i < NN * HH) h[i] = root1[i] + bias1[i & (HH - 1)];
}

// h[dst] += W1[et, src]   (16 lanes per edge, float4 per lane)
__global__ __launch_bounds__(256) void k_edges1(const int* __restrict__ ei,
                                                const int* __restrict__ et,
                                                const float* __restrict__ W1,
                                                float* __restrict__ h) {
    int gid = blockIdx.x * 256 + threadIdx.x;
    int e = gid >> 4;
    int j = gid & 15;
    if (e >= EE) return;
    int s = 0, d = 0, r = 0;
    if (j == 0) { s = ei[e]; d = ei[EE + e]; r = et[e]; }
    s = __shfl(s, 0, 16);
    d = __shfl(d, 0, 16);
    r = __shfl(r, 0, 16);
    const float4 w = *(const float4*)(W1 + ((size_t)r * NN + (size_t)s) * HH + j * 4);
    float* hp = h + (size_t)d * HH + j * 4;
    atomicAdd(hp + 0, w.x);
    atomicAdd(hp + 1, w.y);
    atomicAdd(hp + 2, w.z);
    atomicAdd(hp + 3, w.w);
}

__global__ __launch_bounds__(256) void k_relu(float* __restrict__ h) {
    int i = blockIdx.x * 256 + threadIdx.x;
    if (i < NN * HH) h[i] = fmaxf(h[i], 0.0f);
}

// ---------------------------------------------------------------- layer 2
// tmp[n][c] = sum_k h[n][k] * root2[k][c] + bias2[c]
__global__ __launch_bounds__(256) void k_tmp_init(const float* __restrict__ h,
                                                  const float* __restrict__ root2,
                                                  const float* __restrict__ bias2,
                                                  float* __restrict__ tmp) {
    int i = blockIdx.x * 256 + threadIdx.x;  // 0 .. NN*CC
    if (i >= NN * CC) return;
    int n = i >> 3;
    int c = i & 7;
    const float* hp = h + (size_t)n * HH;
    float acc = bias2[c];
    #pragma unroll
    for (int k = 0; k < HH; k += 4) {
        float4 hv = *(const float4*)(hp + k);
        acc += hv.x * root2[(k + 0) * CC + c];
        acc += hv.y * root2[(k + 1) * CC + c];
        acc += hv.z * root2[(k + 2) * CC + c];
        acc += hv.w * root2[(k + 3) * CC + c];
    }
    tmp[i] = acc;
}

// tmp[dst] += h[src] @ W2[et]   (8 lanes per edge; lane j covers k in [8j,8j+8))
__global__ __launch_bounds__(256) void k_edges2(const int* __restrict__ ei,
                                               const int* __restrict__ et,
                                               const float* __restrict__ W2,
                                               const float* __restrict__ h,
                                               float* __restrict__ tmp) {
    int gid = blockIdx.x * 256 + threadIdx.x;
    int e = gid >> 3;
    int j = gid & 7;
    if (e >= EE) return;
    int s = 0, d = 0, r = 0;
    if (j == 0) { s = ei[e]; d = ei[EE + e]; r = et[e]; }
    s = __shfl(s, 0, 8);
    d = __shfl(d, 0, 8);
    r = __shfl(r, 0, 8);

    const float* hp = h + (size_t)s * HH + j * 8;
    float4 ha = *(const float4*)(hp);
    float4 hb = *(const float4*)(hp + 4);
    float hk[8] = {ha.x, ha.y, ha.z, ha.w, hb.x, hb.y, hb.z, hb.w};

    const float* w2 = W2 + ((size_t)r * HH + j * 8) * CC;
    float acc[8] = {0, 0, 0, 0, 0, 0, 0, 0};
    #pragma unroll
    for (int kk = 0; kk < 8; kk++) {
        float4 wa = *(const float4*)(w2 + kk * CC);
        float4 wb = *(const float4*)(w2 + kk * CC + 4);
        acc[0] += hk[kk] * wa.x;
        acc[1] += hk[kk] * wa.y;
        acc[2] += hk[kk] * wa.z;
        acc[3] += hk[kk] * wa.w;
        acc[4] += hk[kk] * wb.x;
        acc[5] += hk[kk] * wb.y;
        acc[6] += hk[kk] * wb.z;
        acc[7] += hk[kk] * wb.w;
    }
    // reduce the 8 partial vectors across the 8-lane group (butterfly)
    #pragma unroll
    for (int m = 1; m < 8; m <<= 1) {
        #pragma unroll
        for (int c = 0; c < 8; c++) acc[c] += __shfl_xor(acc[c], m, 8);
    }
    // lane j takes channel j (compile-time-unrolled select, no scratch)
    float v = acc[0];
    #pragma unroll
    for (int c = 1; c < 8; c++)
        if (j == c) v = acc[c];
    atomicAdd(tmp + (size_t)d * CC + j, v);
}

// out[n][:] = log_softmax(tmp[n][:])
__global__ __launch_bounds__(256) void k_lsm(const float* __restrict__ tmp,
                                             float* __restrict__ out) {
    int n = blockIdx.x * 256 + threadIdx.x;
    if (n >= NN) return;
    float4 a = *(const float4*)(tmp + (size_t)n * CC);
    float4 b = *(const float4*)(tmp + (size_t)n * CC + 4);
    float x[8] = {a.x, a.y, a.z, a.w, b.x, b.y, b.z, b.w};
    float m = x[0];
    #pragma unroll
    for (int c = 1; c < 8; c++) m = fmaxf(m, x[c]);
    float ssum = 0.0f;
    #pragma unroll
    for (int c = 0; c < 8; c++) ssum += expf(x[c] - m);
    float l = m + logf(ssum);
    float4 oa = make_float4(x[0] - l, x[1] - l, x[2] - l, x[3] - l);
    float4 ob = make_float4(x[4] - l, x[5] - l, x[6] - l, x[7] - l);
    *(float4*)(out + (size_t)n * CC) = oa;
    *(float4*)(out + (size_t)n * CC + 4) = ob;
}

extern "C" void kernel_launch(void* const* d_in, const int* in_sizes, int n_in,
                              void* d_out, int out_size, void* d_ws, size_t ws_size,
                              hipStream_t stream) {
    const int*   ei    = (const int*)d_in[0];    // [2, E]
    const int*   et    = (const int*)d_in[1];    // [E]
    // d_in[2] = tensor_slice (unused; we read edge_type directly)
    const float* W1    = (const float*)d_in[3];  // [R, N, H]
    const float* root1 = (const float*)d_in[4];  // [N, H]
    const float* bias1 = (const float*)d_in[5];  // [H]
    const float* W2    = (const float*)d_in[6];  // [R, H, C]
    const float* root2 = (const float*)d_in[7];  // [H, C]
    const float* bias2 = (const float*)d_in[8];  // [C]
    float* out = (float*)d_out;

    float* h   = (float*)d_ws;           // NN*HH floats
    float* tmp = h + (size_t)NN * HH;    // NN*CC floats

    k_init_h<<<(NN * HH + 255) / 256, 256, 0, stream>>>(root1, bias1, h);
    k_edges1<<<(EE * 16 + 255) / 256, 256, 0, stream>>>(ei, et, W1, h);
    k_relu<<<(NN * HH + 255) / 256, 256, 0, stream>>>(h);
    k_tmp_init<<<(NN * CC + 255) / 256, 256, 0, stream>>>(h, root2, bias2, tmp);
    k_edges2<<<(EE * 8 + 255) / 256, 256, 0, stream>>>(ei, et, W2, h, tmp);
    k_lsm<<<(NN + 255) / 256, 256, 0, stream>>>(tmp, out);
}

// Round 2
// 210.141 us; speedup vs baseline: 3.3997x; 3.3997x over previous
//
#include <hip/hip_runtime.h>
#include <math.h>

#define NN 20000
#define RR 32
#define HH 64
#define CC 8
#define EE 640000

// ---------------------------------------------------------------- CSR build
__global__ __launch_bounds__(256) void k_hist(const int* __restrict__ ei,
                                              int* __restrict__ cnt) {
    int e = blockIdx.x * 256 + threadIdx.x;
    if (e < EE) atomicAdd(&cnt[ei[EE + e]], 1);
}

// single-block scan: off[0..NN] (exclusive prefix), cur[] = scatter cursors
__global__ __launch_bounds__(1024) void k_scan(const int* __restrict__ cnt,
                                               int* __restrict__ off,
                                               int* __restrict__ cur) {
    __shared__ int s[1024];
    __shared__ int sbase;
    int tid = threadIdx.x;
    if (tid == 0) { sbase = 0; off[0] = 0; }
    __syncthreads();
    for (int chunk = 0; chunk < NN; chunk += 1024) {
        int idx = chunk + tid;
        int v = (idx < NN) ? cnt[idx] : 0;
        s[tid] = v;
        __syncthreads();
        int b = sbase;
        for (int st = 1; st < 1024; st <<= 1) {
            int t = (tid >= st) ? s[tid - st] : 0;
            __syncthreads();
            s[tid] += t;
            __syncthreads();
        }
        int inc = s[tid];
        if (idx < NN) { off[idx + 1] = b + inc; cur[idx] = b + inc - v; }
        __syncthreads();
        if (tid == 1023) sbase = b + s[1023];
        __syncthreads();
    }
}

__global__ __launch_bounds__(256) void k_scatter(const int* __restrict__ ei,
                                                 const int* __restrict__ et,
                                                 int* __restrict__ cur,
                                                 unsigned* __restrict__ pk) {
    int e = blockIdx.x * 256 + threadIdx.x;
    if (e >= EE) return;
    int d = ei[EE + e];
    unsigned p = (unsigned)ei[e] | ((unsigned)et[e] << 15);
    int pos = atomicAdd(&cur[d], 1);
    pk[pos] = p;
}

// ---------------------------------------------------------------- layer 1
// wave per dst node; lane owns h element; gather W1 rows, no atomics
__global__ __launch_bounds__(256) void k_gather1(const unsigned* __restrict__ pk,
                                                 const int* __restrict__ off,
                                                 const float* __restrict__ W1,
                                                 const float* __restrict__ root1,
                                                 const float* __restrict__ bias1,
                                                 float* __restrict__ h) {
    int wid = (blockIdx.x * 256 + threadIdx.x) >> 6;
    int lane = threadIdx.x & 63;
    if (wid >= NN) return;
    float acc = root1[(size_t)wid * HH + lane] + bias1[lane];
    int i = off[wid], end = off[wid + 1];
    for (; i + 4 <= end; i += 4) {
        unsigned p0 = pk[i], p1 = pk[i + 1], p2 = pk[i + 2], p3 = pk[i + 3];
        float w0 = W1[((size_t)(p0 >> 15) * NN + (p0 & 0x7fffu)) * HH + lane];
        float w1 = W1[((size_t)(p1 >> 15) * NN + (p1 & 0x7fffu)) * HH + lane];
        float w2 = W1[((size_t)(p2 >> 15) * NN + (p2 & 0x7fffu)) * HH + lane];
        float w3 = W1[((size_t)(p3 >> 15) * NN + (p3 & 0x7fffu)) * HH + lane];
        acc += (w0 + w1) + (w2 + w3);
    }
    for (; i < end; ++i) {
        unsigned p = pk[i];
        acc += W1[((size_t)(p >> 15) * NN + (p & 0x7fffu)) * HH + lane];
    }
    h[(size_t)wid * HH + lane] = fmaxf(acc, 0.0f);
}

// ---------------------------------------------------------------- layer 2
// hrel[r][n][c] = sum_k h[n][k] * W2[r][k][c]
__global__ __launch_bounds__(256) void k_hrel(const float* __restrict__ h,
                                              const float* __restrict__ W2,
                                              float* __restrict__ hrel) {
    __shared__ float w2s[HH * CC];
    int r = blockIdx.y;
    int tid = threadIdx.x;
    w2s[tid]       = W2[(size_t)r * HH * CC + tid];
    w2s[tid + 256] = W2[(size_t)r * HH * CC + tid + 256];
    __syncthreads();
    int i = blockIdx.x * 256 + tid;  // over NN*CC (=160000, exact multiple of 256)
    int n = i >> 3, c = i & 7;
    const float* hp = h + (size_t)n * HH;
    float acc = 0.f;
    #pragma unroll
    for (int k = 0; k < HH; k += 4) {
        float4 hv = *(const float4*)(hp + k);
        acc += hv.x * w2s[(k + 0) * CC + c] + hv.y * w2s[(k + 1) * CC + c]
             + hv.z * w2s[(k + 2) * CC + c] + hv.w * w2s[(k + 3) * CC + c];
    }
    hrel[((size_t)r * NN + n) * CC + c] = acc;
}

// wave per dst node; gather hrel rows; fused root2 + bias2 + log-softmax
__global__ __launch_bounds__(256) void k_gather2(const unsigned* __restrict__ pk,
                                                 const int* __restrict__ off,
                                                 const float* __restrict__ h,
                                                 const float* __restrict__ hrel,
                                                 const float* __restrict__ root2,
                                                 const float* __restrict__ bias2,
                                                 float* __restrict__ out) {
    int wid = (blockIdx.x * 256 + threadIdx.x) >> 6;
    int lane = threadIdx.x & 63;
    if (wid >= NN) return;
    int kg = lane >> 3, c = lane & 7;
    float hn = h[(size_t)wid * HH + lane];
    float acc = 0.f;
    // root2 term: lane (kg,c) covers k in [8kg, 8kg+8)
    #pragma unroll
    for (int t = 0; t < 8; t++)
        acc += __shfl(hn, t, 8) * root2[(kg * 8 + t) * CC + c];
    // edge term: lane (kg,c) covers edges beg+kg, beg+kg+8, ... channel c
    int end = off[wid + 1];
    for (int i = off[wid] + kg; i < end; i += 8) {
        unsigned p = pk[i];
        acc += hrel[((size_t)(p >> 15) * NN + (p & 0x7fffu)) * CC + c];
    }
    // fold the 8 sub-groups (sums both root2-k-chunks and edge partials)
    acc += __shfl_xor(acc, 8);
    acc += __shfl_xor(acc, 16);
    acc += __shfl_xor(acc, 32);
    float x = acc + bias2[c];
    // log-softmax over the 8 channels (lanes differing in bits 0..2)
    float m = x;
    m = fmaxf(m, __shfl_xor(m, 1));
    m = fmaxf(m, __shfl_xor(m, 2));
    m = fmaxf(m, __shfl_xor(m, 4));
    float ex = expf(x - m);
    ex += __shfl_xor(ex, 1);
    ex += __shfl_xor(ex, 2);
    ex += __shfl_xor(ex, 4);
    float l = m + logf(ex);
    if (lane < 8) out[(size_t)wid * CC + lane] = x - l;
}

extern "C" void kernel_launch(void* const* d_in, const int* in_sizes, int n_in,
                              void* d_out, int out_size, void* d_ws, size_t ws_size,
                              hipStream_t stream) {
    const int*   ei    = (const int*)d_in[0];    // [2, E]
    const int*   et    = (const int*)d_in[1];    // [E]
    const float* W1    = (const float*)d_in[3];  // [R, N, H]
    const float* root1 = (const float*)d_in[4];  // [N, H]
    const float* bias1 = (const float*)d_in[5];  // [H]
    const float* W2    = (const float*)d_in[6];  // [R, H, C]
    const float* root2 = (const float*)d_in[7];  // [H, C]
    const float* bias2 = (const float*)d_in[8];  // [C]
    float* out = (float*)d_out;

    char* base = (char*)d_ws;
    int*      cnt  = (int*)(base);                         // NN ints
    int*      cur  = (int*)(base + 80000);                 // NN ints
    int*      off  = (int*)(base + 160000);                // NN+1 ints
    unsigned* pk   = (unsigned*)(base + 240128);           // EE words
    float*    h    = (float*)(base + 2800128);             // NN*HH floats (16B aligned)
    float*    hrel = (float*)(base + 7920128);             // RR*NN*CC floats
    // total ws use: 28,400,128 bytes

    hipMemsetAsync(cnt, 0, NN * sizeof(int), stream);
    k_hist   <<<(EE + 255) / 256, 256, 0, stream>>>(ei, cnt);
    k_scan   <<<1, 1024, 0, stream>>>(cnt, off, cur);
    k_scatter<<<(EE + 255) / 256, 256, 0, stream>>>(ei, et, cur, pk);
    k_gather1<<<(NN * 64 + 255) / 256, 256, 0, stream>>>(pk, off, W1, root1, bias1, h);
    k_hrel   <<<dim3(NN * CC / 256, RR), 256, 0, stream>>>(h, W2, hrel);
    k_gather2<<<(NN * 64 + 255) / 256, 256, 0, stream>>>(pk, off, h, hrel, root2, bias2, out);
}

// Round 3
// 186.245 us; speedup vs baseline: 3.8359x; 1.1283x over previous
//
#include <hip/hip_runtime.h>
#include <math.h>

#define NN 20000
#define RR 32
#define HH 64
#define CC 8
#define EE 640000

// ---------------------------------------------------------------- CSR build
__global__ __launch_bounds__(256) void k_zero(int* __restrict__ cnt) {
    int i = blockIdx.x * 256 + threadIdx.x;
    if (i < NN) cnt[i] = 0;
}

__global__ __launch_bounds__(256) void k_hist(const int* __restrict__ ei,
                                              int* __restrict__ cnt) {
    int e = blockIdx.x * 256 + threadIdx.x;
    if (e < EE) atomicAdd(&cnt[ei[EE + e]], 1);
}

// single-block scan: 1024 threads x 20 elements each (20480 >= NN)
#define SCAN_PER 20
__global__ __launch_bounds__(1024) void k_scan(const int* __restrict__ cnt,
                                               int* __restrict__ off,
                                               int* __restrict__ cur) {
    int tid = threadIdx.x;
    int base = tid * SCAN_PER;
    int v[SCAN_PER];
    int sum = 0;
    #pragma unroll
    for (int u = 0; u < SCAN_PER; u++) {
        int idx = base + u;
        v[u] = (idx < NN) ? cnt[idx] : 0;
        sum += v[u];
    }
    int lane = tid & 63, wv = tid >> 6;
    // inclusive shfl scan of per-thread sums within each wave
    int s = sum;
    #pragma unroll
    for (int st = 1; st < 64; st <<= 1) {
        int t = __shfl_up(s, st, 64);
        if (lane >= st) s += t;
    }
    __shared__ int wsum[16];
    if (lane == 63) wsum[wv] = s;
    __syncthreads();
    if (wv == 0 && lane < 16) {
        int ws = wsum[lane];
        #pragma unroll
        for (int st = 1; st < 16; st <<= 1) {
            int t = __shfl_up(ws, st, 16);
            if (lane >= st) ws += t;
        }
        wsum[lane] = ws;
    }
    __syncthreads();
    int wbase = (wv > 0) ? wsum[wv - 1] : 0;
    int run = wbase + s - sum;  // exclusive prefix for this thread's chunk
    #pragma unroll
    for (int u = 0; u < SCAN_PER; u++) {
        int idx = base + u;
        if (idx < NN) {
            cur[idx] = run;
            run += v[u];
            off[idx + 1] = run;
        }
    }
    if (tid == 0) off[0] = 0;
}

__global__ __launch_bounds__(256) void k_scatter(const int* __restrict__ ei,
                                                 const int* __restrict__ et,
                                                 int* __restrict__ cur,
                                                 unsigned* __restrict__ pk) {
    int e = blockIdx.x * 256 + threadIdx.x;
    if (e >= EE) return;
    int d = ei[EE + e];
    unsigned p = (unsigned)ei[e] | ((unsigned)et[e] << 15);
    int pos = atomicAdd(&cur[d], 1);
    pk[pos] = p;
}

// ---------------------------------------------------------------- layer 1
// wave per dst node; lane owns h element; gather W1 rows, no atomics
__global__ __launch_bounds__(256) void k_gather1(const unsigned* __restrict__ pk,
                                                 const int* __restrict__ off,
                                                 const float* __restrict__ W1,
                                                 const float* __restrict__ root1,
                                                 const float* __restrict__ bias1,
                                                 float* __restrict__ h) {
    int wid = (blockIdx.x * 256 + threadIdx.x) >> 6;
    int lane = threadIdx.x & 63;
    if (wid >= NN) return;
    float acc = root1[(size_t)wid * HH + lane] + bias1[lane];
    int i = off[wid], end = off[wid + 1];
    for (; i + 4 <= end; i += 4) {
        unsigned p0 = pk[i], p1 = pk[i + 1], p2 = pk[i + 2], p3 = pk[i + 3];
        float w0 = W1[((size_t)(p0 >> 15) * NN + (p0 & 0x7fffu)) * HH + lane];
        float w1 = W1[((size_t)(p1 >> 15) * NN + (p1 & 0x7fffu)) * HH + lane];
        float w2 = W1[((size_t)(p2 >> 15) * NN + (p2 & 0x7fffu)) * HH + lane];
        float w3 = W1[((size_t)(p3 >> 15) * NN + (p3 & 0x7fffu)) * HH + lane];
        acc += (w0 + w1) + (w2 + w3);
    }
    for (; i < end; ++i) {
        unsigned p = pk[i];
        acc += W1[((size_t)(p >> 15) * NN + (p & 0x7fffu)) * HH + lane];
    }
    h[(size_t)wid * HH + lane] = fmaxf(acc, 0.0f);
}

// ---------------------------------------------------------------- layer 2
// thread per (r, n): hrel[r][n][c] = sum_k h[n][k] * W2[r][k][c]
__global__ __launch_bounds__(256) void k_hrel(const float* __restrict__ h,
                                              const float* __restrict__ W2,
                                              float* __restrict__ hrel) {
    __shared__ float w2s[HH * CC];
    int r = blockIdx.y;
    int tid = threadIdx.x;
    w2s[tid]       = W2[(size_t)r * HH * CC + tid];
    w2s[tid + 256] = W2[(size_t)r * HH * CC + tid + 256];
    __syncthreads();
    int n = blockIdx.x * 256 + tid;
    if (n >= NN) return;
    const float* hp = h + (size_t)n * HH;
    float acc[CC] = {0, 0, 0, 0, 0, 0, 0, 0};
    #pragma unroll
    for (int k = 0; k < HH; k += 4) {
        float4 hv = *(const float4*)(hp + k);
        #pragma unroll
        for (int c = 0; c < CC; c++) {
            acc[c] += hv.x * w2s[(k + 0) * CC + c] + hv.y * w2s[(k + 1) * CC + c]
                    + hv.z * w2s[(k + 2) * CC + c] + hv.w * w2s[(k + 3) * CC + c];
        }
    }
    float* op = hrel + ((size_t)r * NN + n) * CC;
    *(float4*)(op)     = make_float4(acc[0], acc[1], acc[2], acc[3]);
    *(float4*)(op + 4) = make_float4(acc[4], acc[5], acc[6], acc[7]);
}

// wave per dst node; gather hrel rows; fused root2 + bias2 + log-softmax
__global__ __launch_bounds__(256) void k_gather2(const unsigned* __restrict__ pk,
                                                 const int* __restrict__ off,
                                                 const float* __restrict__ h,
                                                 const float* __restrict__ hrel,
                                                 const float* __restrict__ root2,
                                                 const float* __restrict__ bias2,
                                                 float* __restrict__ out) {
    int wid = (blockIdx.x * 256 + threadIdx.x) >> 6;
    int lane = threadIdx.x & 63;
    if (wid >= NN) return;
    int kg = lane >> 3, c = lane & 7;
    float hn = h[(size_t)wid * HH + lane];
    float acc = 0.f;
    // root2 term: lane (kg,c) covers k in [8kg, 8kg+8)
    #pragma unroll
    for (int t = 0; t < 8; t++)
        acc += __shfl(hn, t, 8) * root2[(kg * 8 + t) * CC + c];
    // edge term: lane (kg,c) covers edges beg+kg, beg+kg+8, ... channel c
    int end = off[wid + 1];
    for (int i = off[wid] + kg; i < end; i += 8) {
        unsigned p = pk[i];
        acc += hrel[((size_t)(p >> 15) * NN + (p & 0x7fffu)) * CC + c];
    }
    // fold the 8 sub-groups
    acc += __shfl_xor(acc, 8);
    acc += __shfl_xor(acc, 16);
    acc += __shfl_xor(acc, 32);
    float x = acc + bias2[c];
    // log-softmax over the 8 channels (lanes differing in bits 0..2)
    float m = x;
    m = fmaxf(m, __shfl_xor(m, 1));
    m = fmaxf(m, __shfl_xor(m, 2));
    m = fmaxf(m, __shfl_xor(m, 4));
    float ex = expf(x - m);
    ex += __shfl_xor(ex, 1);
    ex += __shfl_xor(ex, 2);
    ex += __shfl_xor(ex, 4);
    float l = m + logf(ex);
    if (lane < 8) out[(size_t)wid * CC + lane] = x - l;
}

extern "C" void kernel_launch(void* const* d_in, const int* in_sizes, int n_in,
                              void* d_out, int out_size, void* d_ws, size_t ws_size,
                              hipStream_t stream) {
    const int*   ei    = (const int*)d_in[0];    // [2, E]
    const int*   et    = (const int*)d_in[1];    // [E]
    const float* W1    = (const float*)d_in[3];  // [R, N, H]
    const float* root1 = (const float*)d_in[4];  // [N, H]
    const float* bias1 = (const float*)d_in[5];  // [H]
    const float* W2    = (const float*)d_in[6];  // [R, H, C]
    const float* root2 = (const float*)d_in[7];  // [H, C]
    const float* bias2 = (const float*)d_in[8];  // [C]
    float* out = (float*)d_out;

    char* base = (char*)d_ws;
    int*      cnt  = (int*)(base);                         // NN ints
    int*      cur  = (int*)(base + 80000);                 // NN ints
    int*      off  = (int*)(base + 160000);                // NN+1 ints
    unsigned* pk   = (unsigned*)(base + 240128);           // EE words
    float*    h    = (float*)(base + 2800128);             // NN*HH floats
    float*    hrel = (float*)(base + 7920128);             // RR*NN*CC floats
    // total ws use: 28,400,128 bytes

    k_zero   <<<(NN + 255) / 256, 256, 0, stream>>>(cnt);
    k_hist   <<<(EE + 255) / 256, 256, 0, stream>>>(ei, cnt);
    k_scan   <<<1, 1024, 0, stream>>>(cnt, off, cur);
    k_scatter<<<(EE + 255) / 256, 256, 0, stream>>>(ei, et, cur, pk);
    k_gather1<<<(NN * 64 + 255) / 256, 256, 0, stream>>>(pk, off, W1, root1, bias1, h);
    k_hrel   <<<dim3((NN + 255) / 256, RR), 256, 0, stream>>>(h, W2, hrel);
    k_gather2<<<(NN * 64 + 255) / 256, 256, 0, stream>>>(pk, off, h, hrel, root2, bias2, out);
}